// Round 3
// baseline (748.902 us; speedup 1.0000x reference)
//
#include <hip/hip_runtime.h>
#include <hip/hip_bf16.h>

#define NEG_SLOPE 0.2f

__device__ __forceinline__ float wave_max64(float v) {
    for (int o = 32; o; o >>= 1) v = fmaxf(v, __shfl_xor(v, o));
    return v;
}
__device__ __forceinline__ float wave_sum64(float v) {
    for (int o = 32; o; o >>= 1) v += __shfl_xor(v, o);
    return v;
}
__device__ __forceinline__ unsigned short f2bf(float f) {
    unsigned int u = __float_as_uint(f);
    unsigned int r = (u + 0x7fffu + ((u >> 16) & 1u)) >> 16;
    return (unsigned short)r;
}
__device__ __forceinline__ float bf2f(unsigned short u) {
    return __uint_as_float(((unsigned int)u) << 16);
}

// ---------------- CSR build ----------------

__global__ void k_hist(const int* __restrict__ dst, int* __restrict__ deg, int E) {
    int e = blockIdx.x * blockDim.x + threadIdx.x;
    if (e < E) atomicAdd(&deg[dst[e]], 1);
}

__global__ __launch_bounds__(1024) void k_scan(const int* __restrict__ deg,
                                               int* __restrict__ row_start, int n) {
    __shared__ int sdata[1024];
    int tid = threadIdx.x;
    const int per = 52;  // multiple of 4 covering 50000/1024
    int begin = tid * per;
    int end = begin + per; if (end > n) end = n;
    int sum = 0;
    int i = begin;
    for (; i + 3 < end; i += 4) {
        int4 v = *reinterpret_cast<const int4*>(deg + i);
        sum += v.x + v.y + v.z + v.w;
    }
    for (; i < end; i++) sum += deg[i];
    sdata[tid] = sum;
    __syncthreads();
    for (int off = 1; off < 1024; off <<= 1) {
        int t = (tid >= off) ? sdata[tid - off] : 0;
        __syncthreads();
        sdata[tid] += t;
        __syncthreads();
    }
    int run = sdata[tid] - sum;
    for (int j = begin; j < end; j++) { row_start[j] = run; run += deg[j]; }
    if (tid == 1023) row_start[n] = sdata[1023];
}

// scatter: bucket edges by dst, storing the SRC NODE ID directly (no edge indirection)
__global__ void k_scatter(const int* __restrict__ dst, const int* __restrict__ src,
                          const int* __restrict__ row_start, int* __restrict__ cursor,
                          int* __restrict__ ssrc, int E) {
    int e = blockIdx.x * blockDim.x + threadIdx.x;
    if (e < E) {
        int d = dst[e];
        int pos = row_start[d] + atomicAdd(&cursor[d], 1);
        ssrc[pos] = src[e];
    }
}

// ---------------- Layer 1 GEMM: z1(bf16) = feat @ W1, fused el1/er1, fused gcnt ----------------

__global__ __launch_bounds__(256) void k_gemm1(const float* __restrict__ feat,
                                               const float* __restrict__ W1,
                                               const float* __restrict__ al,
                                               const float* __restrict__ ar,
                                               const int* __restrict__ gid,
                                               unsigned short* __restrict__ z1,
                                               float4* __restrict__ el1,
                                               float4* __restrict__ er1,
                                               int* __restrict__ gcnt, int n) {
    __shared__ float sW[960], sal[96], sar[96];
    for (int i = threadIdx.x; i < 960; i += 256) sW[i] = W1[i];
    for (int i = threadIdx.x; i < 96; i += 256) { sal[i] = al[i]; sar[i] = ar[i]; }
    __syncthreads();
    int nd = blockIdx.x * 256 + threadIdx.x;
    if (nd >= n) return;
    atomicAdd(&gcnt[gid[nd]], 1);
    float x[10];
#pragma unroll
    for (int k = 0; k < 10; k++) x[k] = feat[(size_t)nd * 10 + k];
    float el[3] = {0.f, 0.f, 0.f}, er[3] = {0.f, 0.f, 0.f};
#pragma unroll
    for (int h = 0; h < 3; h++) {
#pragma unroll
        for (int d0 = 0; d0 < 32; d0 += 4) {
            ushort4 o;
            unsigned short* op = &o.x;
#pragma unroll
            for (int q = 0; q < 4; q++) {
                int c = h * 32 + d0 + q;
                float acc = 0.f;
#pragma unroll
                for (int k = 0; k < 10; k++) acc += x[k] * sW[k * 96 + c];
                op[q] = f2bf(acc);
                el[h] += acc * sal[c];
                er[h] += acc * sar[c];
            }
            *reinterpret_cast<ushort4*>(&z1[(size_t)nd * 96 + h * 32 + d0]) = o;
        }
    }
    el1[nd] = make_float4(el[0], el[1], el[2], 0.f);
    er1[nd] = make_float4(er[0], er[1], er[2], 0.f);
}

// ---------------- GAT aggregation: wave per dst node ----------------
// z is bf16. VW = bf16 columns per lane (2 for HD=96, 4 for HD=192); NL = HD/VW = 48 lanes used.
// POOL: instead of writing the output row, relu + atomicAdd into gsum[graph].

template <int D, int VW, bool POOL>
__global__ __launch_bounds__(256) void k_agg(const unsigned short* __restrict__ z,
                                             const float4* __restrict__ el,
                                             const float4* __restrict__ er,
                                             const int* __restrict__ row_start,
                                             const int* __restrict__ ssrc,
                                             float* __restrict__ xout,
                                             const int* __restrict__ gid,
                                             float* __restrict__ gsum, int n) {
    constexpr int H = 3;
    constexpr int HD = H * D;
    constexpr int NL = HD / VW;  // 48
    __shared__ float pl[4][3 * 68];
    int wid = (blockIdx.x * blockDim.x + threadIdx.x) >> 6;
    int lane = threadIdx.x & 63;
    int w = threadIdx.x >> 6;
    if (wid >= n) return;
    int s0 = row_start[wid];
    int deg = row_start[wid + 1] - s0;
    if (deg <= 0) {
        if constexpr (!POOL) {
            float* orow = xout + (size_t)wid * HD;
            int col = VW * lane;
            if (lane < NL) {
                if constexpr (VW == 2)
                    *reinterpret_cast<float2*>(orow + col) = make_float2(0.f, 0.f);
                else
                    *reinterpret_cast<float4*>(orow + col) = make_float4(0.f, 0.f, 0.f, 0.f);
            }
        }
        return;
    }
    float4 erv = er[wid];
    int hh = (VW * lane) / D;
    if (hh >= H) hh = H - 1;

    if (deg <= 64) {
        bool act = lane < deg;
        int sv = act ? ssrc[s0 + lane] : 0;
        float4 elv = el[sv];
        float v0 = elv.x + erv.x; v0 = v0 > 0.f ? v0 : NEG_SLOPE * v0;
        float v1 = elv.y + erv.y; v1 = v1 > 0.f ? v1 : NEG_SLOPE * v1;
        float v2 = elv.z + erv.z; v2 = v2 > 0.f ? v2 : NEG_SLOPE * v2;
        if (!act) { v0 = -3.402823466e38f; v1 = v0; v2 = v0; }
        float m0 = wave_max64(v0), m1 = wave_max64(v1), m2 = wave_max64(v2);
        float p0 = act ? __expf(v0 - m0) : 0.f;
        float p1 = act ? __expf(v1 - m1) : 0.f;
        float p2 = act ? __expf(v2 - m2) : 0.f;
        float i0 = 1.f / (wave_sum64(p0) + 1e-16f);
        float i1 = 1.f / (wave_sum64(p1) + 1e-16f);
        float i2 = 1.f / (wave_sum64(p2) + 1e-16f);
        // normalized attention table, one slot per head (padded stride 68)
        pl[w][0 * 68 + lane] = p0 * i0;
        pl[w][1 * 68 + lane] = p1 * i1;
        pl[w][2 * 68 + lane] = p2 * i2;
        int zofs = sv * HD;
        const float* pt = &pl[w][hh * 68];

        int col = VW * (lane < NL ? lane : NL - 1);
        float acc0 = 0.f, acc1 = 0.f, acc2 = 0.f, acc3 = 0.f;
#pragma unroll 4
        for (int i = 0; i < deg; i++) {
            int zo = __shfl(zofs, i);
            float a = pt[i];
            const unsigned short* zp = z + zo + col;
            if constexpr (VW == 2) {
                ushort2 zv = *reinterpret_cast<const ushort2*>(zp);
                acc0 += a * bf2f(zv.x); acc1 += a * bf2f(zv.y);
            } else {
                ushort4 zv = *reinterpret_cast<const ushort4*>(zp);
                acc0 += a * bf2f(zv.x); acc1 += a * bf2f(zv.y);
                acc2 += a * bf2f(zv.z); acc3 += a * bf2f(zv.w);
            }
        }
        if (lane < NL) {
            if constexpr (POOL) {
                int g = gid[wid];
                float* gp = gsum + g * 192 + col;
                atomicAdd(gp + 0, fmaxf(acc0, 0.f));
                atomicAdd(gp + 1, fmaxf(acc1, 0.f));
                if constexpr (VW == 4) {
                    atomicAdd(gp + 2, fmaxf(acc2, 0.f));
                    atomicAdd(gp + 3, fmaxf(acc3, 0.f));
                }
            } else {
                float* orow = xout + (size_t)wid * HD;
                if constexpr (VW == 2) {
                    *reinterpret_cast<float2*>(orow + col) =
                        make_float2(fmaxf(acc0, 0.f), fmaxf(acc1, 0.f));
                } else {
                    *reinterpret_cast<float4*>(orow + col) =
                        make_float4(fmaxf(acc0, 0.f), fmaxf(acc1, 0.f),
                                    fmaxf(acc2, 0.f), fmaxf(acc3, 0.f));
                }
            }
        }
    } else {
        // ---- fallback 3-pass (deg > 64; astronomically rare, correctness-only) ----
        float ern[3] = {erv.x, erv.y, erv.z};
        float m[3] = {-3.402823466e38f, -3.402823466e38f, -3.402823466e38f};
        for (int i = lane; i < deg; i += 64) {
            int sv = ssrc[s0 + i];
            float4 elv = el[sv];
            float vv[3] = {elv.x, elv.y, elv.z};
#pragma unroll
            for (int h = 0; h < 3; h++) {
                float v = vv[h] + ern[h];
                v = v > 0.f ? v : NEG_SLOPE * v;
                m[h] = fmaxf(m[h], v);
            }
        }
#pragma unroll
        for (int h = 0; h < 3; h++) m[h] = wave_max64(m[h]);
        float s[3] = {0.f, 0.f, 0.f};
        for (int i = lane; i < deg; i += 64) {
            int sv = ssrc[s0 + i];
            float4 elv = el[sv];
            float vv[3] = {elv.x, elv.y, elv.z};
#pragma unroll
            for (int h = 0; h < 3; h++) {
                float v = vv[h] + ern[h];
                v = v > 0.f ? v : NEG_SLOPE * v;
                s[h] += __expf(v - m[h]);
            }
        }
#pragma unroll
        for (int h = 0; h < 3; h++) s[h] = 1.f / (wave_sum64(s[h]) + 1e-16f);
        constexpr int NC = (HD + 63) / 64;
        float acc[NC];
#pragma unroll
        for (int j = 0; j < NC; j++) acc[j] = 0.f;
        for (int i = 0; i < deg; i++) {
            int sv = ssrc[s0 + i];
            float4 elv = el[sv];
            float vv[3] = {elv.x, elv.y, elv.z};
            float a[3];
#pragma unroll
            for (int h = 0; h < 3; h++) {
                float v = vv[h] + ern[h];
                v = v > 0.f ? v : NEG_SLOPE * v;
                a[h] = __expf(v - m[h]) * s[h];
            }
            const unsigned short* zr = z + (size_t)sv * HD;
#pragma unroll
            for (int j = 0; j < NC; j++) {
                int c = lane + 64 * j;
                if (c < HD) acc[j] += a[c / D] * bf2f(zr[c]);
            }
        }
#pragma unroll
        for (int j = 0; j < NC; j++) {
            int c = lane + 64 * j;
            if (c < HD) {
                float o = fmaxf(acc[j], 0.f);
                if constexpr (POOL)
                    atomicAdd(&gsum[gid[wid] * 192 + c], o);
                else
                    xout[(size_t)wid * HD + c] = o;
            }
        }
    }
}

// ---------------- Layer 2 GEMM: z2(bf16) = x1 @ W2 (50000x96 @ 96x192), fused el2/er2 ----------------

__global__ __launch_bounds__(256) void k_gemm2(const float* __restrict__ A,
                                               const float* __restrict__ B,
                                               const float* __restrict__ al,
                                               const float* __restrict__ ar,
                                               unsigned short* __restrict__ C,
                                               float* __restrict__ el2,
                                               float* __restrict__ er2, int M) {
    __shared__ float sAT[16][68];  // transposed: [k][row], 16B-aligned rows
    __shared__ float sB[16][64];
    int t = threadIdx.x;
    int n0 = blockIdx.x * 64;
    int h = blockIdx.y;  // head: columns c0..c0+63
    int c0 = h * 64;
    int ty = t >> 4, tx = t & 15;
    float acc[4][4] = {};
    for (int k0 = 0; k0 < 96; k0 += 16) {
        int arow = t >> 2, aq = (t & 3) * 4;
        float4 av = make_float4(0.f, 0.f, 0.f, 0.f);
        if (n0 + arow < M)
            av = *reinterpret_cast<const float4*>(&A[(size_t)(n0 + arow) * 96 + k0 + aq]);
        sAT[aq + 0][arow] = av.x; sAT[aq + 1][arow] = av.y;
        sAT[aq + 2][arow] = av.z; sAT[aq + 3][arow] = av.w;
        int brow = t >> 4, bq = (t & 15) * 4;
        float4 bv = *reinterpret_cast<const float4*>(&B[(size_t)(k0 + brow) * 192 + c0 + bq]);
        *reinterpret_cast<float4*>(&sB[brow][bq]) = bv;
        __syncthreads();
#pragma unroll
        for (int kk = 0; kk < 16; kk++) {
            float4 a4 = *reinterpret_cast<const float4*>(&sAT[kk][ty * 4]);
            float4 b4 = *reinterpret_cast<const float4*>(&sB[kk][tx * 4]);
            float a[4] = {a4.x, a4.y, a4.z, a4.w};
            float b[4] = {b4.x, b4.y, b4.z, b4.w};
#pragma unroll
            for (int i = 0; i < 4; i++)
#pragma unroll
                for (int j = 0; j < 4; j++) acc[i][j] += a[i] * b[j];
        }
        __syncthreads();
    }
    float alv[4], arv[4];
#pragma unroll
    for (int j = 0; j < 4; j++) {
        alv[j] = al[c0 + tx * 4 + j];
        arv[j] = ar[c0 + tx * 4 + j];
    }
#pragma unroll
    for (int i = 0; i < 4; i++) {
        int r = n0 + ty * 4 + i;
        float pls = 0.f, prs = 0.f;
#pragma unroll
        for (int j = 0; j < 4; j++) { pls += acc[i][j] * alv[j]; prs += acc[i][j] * arv[j]; }
#pragma unroll
        for (int o = 1; o < 16; o <<= 1) { pls += __shfl_xor(pls, o); prs += __shfl_xor(prs, o); }
        if (r < M) {
            ushort4 o4;
            o4.x = f2bf(acc[i][0]); o4.y = f2bf(acc[i][1]);
            o4.z = f2bf(acc[i][2]); o4.w = f2bf(acc[i][3]);
            *reinterpret_cast<ushort4*>(&C[(size_t)r * 192 + c0 + tx * 4]) = o4;
            if (tx == 0) { el2[r * 4 + h] = pls; er2[r * 4 + h] = prs; }
        }
    }
}

// ---------------- MLP head: one wave per graph ----------------

__global__ __launch_bounds__(64) void k_head(const float* __restrict__ gsum,
                                             const int* __restrict__ gcnt,
                                             const float* __restrict__ d1w,
                                             const float* __restrict__ d1b,
                                             const float* __restrict__ d2w,
                                             const float* __restrict__ d2b,
                                             float* __restrict__ out, int G) {
    int g = blockIdx.x, j = threadIdx.x;
    float inv = 1.f / fmaxf((float)gcnt[g], 1.f);
    float h = d1b[j];
    for (int k = 0; k < 192; k++) h += (gsum[g * 192 + k] * inv) * d1w[(size_t)k * 64 + j];
    h = fmaxf(h, 0.f);
    float v = h * d2w[j];
    for (int off = 32; off; off >>= 1) v += __shfl_xor(v, off);
    if (j == 0) out[g] = v + d2b[0];
}

// ---------------- launch ----------------

extern "C" void kernel_launch(void* const* d_in, const int* in_sizes, int n_in,
                              void* d_out, int out_size, void* d_ws, size_t ws_size,
                              hipStream_t stream) {
    const float* feat = (const float*)d_in[0];
    const int* src = (const int*)d_in[1];
    const int* dst = (const int*)d_in[2];
    const int* gid = (const int*)d_in[3];
    const float* W1 = (const float*)d_in[4];
    const float* al1 = (const float*)d_in[5];
    const float* ar1 = (const float*)d_in[6];
    const float* W2 = (const float*)d_in[7];
    const float* al2 = (const float*)d_in[8];
    const float* ar2 = (const float*)d_in[9];
    const float* d1w = (const float*)d_in[10];
    const float* d1b = (const float*)d_in[11];
    const float* d2w = (const float*)d_in[12];
    const float* d2b = (const float*)d_in[13];
    float* out = (float*)d_out;
    const int N = in_sizes[0] / 10;   // 50000
    const int E = in_sizes[1];        // 800000
    const int G = out_size;           // 128

    char* p = (char*)d_ws;
    auto take = [&](size_t bytes) -> char* {
        char* r = p;
        p += (bytes + 255) & ~(size_t)255;
        return r;
    };
    unsigned short* z1 = (unsigned short*)take((size_t)N * 96 * 2);
    float* x1 = (float*)take((size_t)N * 96 * 4);
    unsigned short* z2 = (unsigned short*)take((size_t)N * 192 * 2);
    float4* el1 = (float4*)take((size_t)N * 16);
    float4* er1 = (float4*)take((size_t)N * 16);
    float* el2 = (float*)take((size_t)N * 16);
    float* er2 = (float*)take((size_t)N * 16);
    int* deg = (int*)take((size_t)N * 4);
    int* row_start = (int*)take((size_t)(N + 1) * 4);
    int* cursor = (int*)take((size_t)N * 4);
    int* ssrc = (int*)take((size_t)E * 4);
    float* gsum = (float*)take((size_t)G * 192 * 4);
    int* gcnt = (int*)take((size_t)G * 4);

    hipMemsetAsync(deg, 0, (size_t)N * 4, stream);
    hipMemsetAsync(cursor, 0, (size_t)N * 4, stream);
    hipMemsetAsync(gsum, 0, (size_t)G * 192 * 4, stream);
    hipMemsetAsync(gcnt, 0, (size_t)G * 4, stream);

    // CSR build (bucket src ids by dst)
    k_hist<<<(E + 255) / 256, 256, 0, stream>>>(dst, deg, E);
    k_scan<<<1, 1024, 0, stream>>>(deg, row_start, N);
    k_scatter<<<(E + 255) / 256, 256, 0, stream>>>(dst, src, row_start, cursor, ssrc, E);

    // Layer 1
    k_gemm1<<<(N + 255) / 256, 256, 0, stream>>>(feat, W1, al1, ar1, gid, z1, el1, er1, gcnt, N);
    k_agg<32, 2, false><<<((size_t)N * 64 + 255) / 256, 256, 0, stream>>>(
        z1, el1, er1, row_start, ssrc, x1, nullptr, nullptr, N);
    // Layer 2 (el2/er2 fused into GEMM epilogue)
    k_gemm2<<<dim3((N + 63) / 64, 3), 256, 0, stream>>>(x1, W2, al2, ar2, z2, el2, er2, N);
    k_agg<64, 4, true><<<((size_t)N * 64 + 255) / 256, 256, 0, stream>>>(
        z2, (const float4*)el2, (const float4*)er2, row_start, ssrc, nullptr, gid, gsum, N);
    // Head (pool fused into agg2)
    k_head<<<G, 64, 0, stream>>>(gsum, gcnt, d1w, d1b, d2w, d2b, out, G);
}

// Round 4
// 575.410 us; speedup vs baseline: 1.3015x; 1.3015x over previous
//
#include <hip/hip_runtime.h>
#include <hip/hip_bf16.h>

#define NEG_SLOPE 0.2f

__device__ __forceinline__ float wave_max64(float v) {
    for (int o = 32; o; o >>= 1) v = fmaxf(v, __shfl_xor(v, o));
    return v;
}
__device__ __forceinline__ float wave_sum64(float v) {
    for (int o = 32; o; o >>= 1) v += __shfl_xor(v, o);
    return v;
}
__device__ __forceinline__ unsigned short f2bf(float f) {
    unsigned int u = __float_as_uint(f);
    unsigned int r = (u + 0x7fffu + ((u >> 16) & 1u)) >> 16;
    return (unsigned short)r;
}
__device__ __forceinline__ float bf2f(unsigned short u) {
    return __uint_as_float(((unsigned int)u) << 16);
}

// ---------------- CSR build ----------------

__global__ void k_hist(const int* __restrict__ dst, int* __restrict__ deg, int E) {
    int e = blockIdx.x * blockDim.x + threadIdx.x;
    if (e < E) atomicAdd(&deg[dst[e]], 1);
}

__global__ __launch_bounds__(1024) void k_scan(const int* __restrict__ deg,
                                               int* __restrict__ row_start, int n) {
    __shared__ int sdata[1024];
    int tid = threadIdx.x;
    const int per = 52;
    int begin = tid * per;
    int end = begin + per; if (end > n) end = n;
    int sum = 0;
    int i = begin;
    for (; i + 3 < end; i += 4) {
        int4 v = *reinterpret_cast<const int4*>(deg + i);
        sum += v.x + v.y + v.z + v.w;
    }
    for (; i < end; i++) sum += deg[i];
    sdata[tid] = sum;
    __syncthreads();
    for (int off = 1; off < 1024; off <<= 1) {
        int t = (tid >= off) ? sdata[tid - off] : 0;
        __syncthreads();
        sdata[tid] += t;
        __syncthreads();
    }
    int run = sdata[tid] - sum;
    for (int j = begin; j < end; j++) { row_start[j] = run; run += deg[j]; }
    if (tid == 1023) row_start[n] = sdata[1023];
}

__global__ void k_scatter(const int* __restrict__ dst, const int* __restrict__ src,
                          const int* __restrict__ row_start, int* __restrict__ cursor,
                          int* __restrict__ ssrc, int E) {
    int e = blockIdx.x * blockDim.x + threadIdx.x;
    if (e < E) {
        int d = dst[e];
        int pos = row_start[d] + atomicAdd(&cursor[d], 1);
        ssrc[pos] = src[e];
    }
}

// ---------------- Layer 1 GEMM: z1(bf16) = feat @ W1, fused el1/er1, fused gcnt ----------------

__global__ __launch_bounds__(256) void k_gemm1(const float* __restrict__ feat,
                                               const float* __restrict__ W1,
                                               const float* __restrict__ al,
                                               const float* __restrict__ ar,
                                               const int* __restrict__ gid,
                                               unsigned short* __restrict__ z1,
                                               float4* __restrict__ el1,
                                               float4* __restrict__ er1,
                                               int* __restrict__ gcnt, int n) {
    __shared__ float sW[960], sal[96], sar[96];
    for (int i = threadIdx.x; i < 960; i += 256) sW[i] = W1[i];
    for (int i = threadIdx.x; i < 96; i += 256) { sal[i] = al[i]; sar[i] = ar[i]; }
    __syncthreads();
    int nd = blockIdx.x * 256 + threadIdx.x;
    if (nd >= n) return;
    atomicAdd(&gcnt[gid[nd]], 1);
    float x[10];
#pragma unroll
    for (int k = 0; k < 10; k++) x[k] = feat[(size_t)nd * 10 + k];
    float el[3] = {0.f, 0.f, 0.f}, er[3] = {0.f, 0.f, 0.f};
#pragma unroll
    for (int h = 0; h < 3; h++) {
#pragma unroll
        for (int d0 = 0; d0 < 32; d0 += 4) {
            ushort4 o;
            unsigned short* op = &o.x;
#pragma unroll
            for (int q = 0; q < 4; q++) {
                int c = h * 32 + d0 + q;
                float acc = 0.f;
#pragma unroll
                for (int k = 0; k < 10; k++) acc += x[k] * sW[k * 96 + c];
                op[q] = f2bf(acc);
                el[h] += acc * sal[c];
                er[h] += acc * sar[c];
            }
            *reinterpret_cast<ushort4*>(&z1[(size_t)nd * 96 + h * 32 + d0]) = o;
        }
    }
    el1[nd] = make_float4(el[0], el[1], el[2], 0.f);
    er1[nd] = make_float4(er[0], er[1], er[2], 0.f);
}

// ---------------- GAT aggregation: wave per dst node ----------------
// z is bf16. VW = bf16 columns per lane (2 for HD=96 -> fp32 out; 4 for HD=192 -> bf16 out).

template <int D, int VW>
__global__ __launch_bounds__(256) void k_agg(const unsigned short* __restrict__ z,
                                             const float4* __restrict__ el,
                                             const float4* __restrict__ er,
                                             const int* __restrict__ row_start,
                                             const int* __restrict__ ssrc,
                                             void* __restrict__ xout_v, int n) {
    constexpr int H = 3;
    constexpr int HD = H * D;
    constexpr int NL = HD / VW;  // 48
    __shared__ float pl[4][3 * 68];
    int wid = (blockIdx.x * blockDim.x + threadIdx.x) >> 6;
    int lane = threadIdx.x & 63;
    int w = threadIdx.x >> 6;
    if (wid >= n) return;
    int s0 = row_start[wid];
    int deg = row_start[wid + 1] - s0;
    if (deg <= 0) {
        if (lane < NL) {
            if constexpr (VW == 2) {
                float* orow = (float*)xout_v + (size_t)wid * HD;
                *reinterpret_cast<float2*>(orow + VW * lane) = make_float2(0.f, 0.f);
            } else {
                unsigned short* orow = (unsigned short*)xout_v + (size_t)wid * HD;
                *reinterpret_cast<ushort4*>(orow + VW * lane) = make_ushort4(0, 0, 0, 0);
            }
        }
        return;
    }
    float4 erv = er[wid];
    int hh = (VW * lane) / D;
    if (hh >= H) hh = H - 1;

    if (deg <= 64) {
        bool act = lane < deg;
        int sv = act ? ssrc[s0 + lane] : 0;
        float4 elv = el[sv];
        float v0 = elv.x + erv.x; v0 = v0 > 0.f ? v0 : NEG_SLOPE * v0;
        float v1 = elv.y + erv.y; v1 = v1 > 0.f ? v1 : NEG_SLOPE * v1;
        float v2 = elv.z + erv.z; v2 = v2 > 0.f ? v2 : NEG_SLOPE * v2;
        if (!act) { v0 = -3.402823466e38f; v1 = v0; v2 = v0; }
        float m0 = wave_max64(v0), m1 = wave_max64(v1), m2 = wave_max64(v2);
        float p0 = act ? __expf(v0 - m0) : 0.f;
        float p1 = act ? __expf(v1 - m1) : 0.f;
        float p2 = act ? __expf(v2 - m2) : 0.f;
        float i0 = 1.f / (wave_sum64(p0) + 1e-16f);
        float i1 = 1.f / (wave_sum64(p1) + 1e-16f);
        float i2 = 1.f / (wave_sum64(p2) + 1e-16f);
        pl[w][0 * 68 + lane] = p0 * i0;
        pl[w][1 * 68 + lane] = p1 * i1;
        pl[w][2 * 68 + lane] = p2 * i2;
        int zofs = sv * HD;
        const float* pt = &pl[w][hh * 68];

        int col = VW * (lane < NL ? lane : NL - 1);
        float acc0 = 0.f, acc1 = 0.f, acc2 = 0.f, acc3 = 0.f;
#pragma unroll 4
        for (int i = 0; i < deg; i++) {
            int zo = __shfl(zofs, i);
            float a = pt[i];
            const unsigned short* zp = z + zo + col;
            if constexpr (VW == 2) {
                ushort2 zv = *reinterpret_cast<const ushort2*>(zp);
                acc0 += a * bf2f(zv.x); acc1 += a * bf2f(zv.y);
            } else {
                ushort4 zv = *reinterpret_cast<const ushort4*>(zp);
                acc0 += a * bf2f(zv.x); acc1 += a * bf2f(zv.y);
                acc2 += a * bf2f(zv.z); acc3 += a * bf2f(zv.w);
            }
        }
        if (lane < NL) {
            if constexpr (VW == 2) {
                float* orow = (float*)xout_v + (size_t)wid * HD;
                *reinterpret_cast<float2*>(orow + col) =
                    make_float2(fmaxf(acc0, 0.f), fmaxf(acc1, 0.f));
            } else {
                unsigned short* orow = (unsigned short*)xout_v + (size_t)wid * HD;
                ushort4 o4;
                o4.x = f2bf(fmaxf(acc0, 0.f)); o4.y = f2bf(fmaxf(acc1, 0.f));
                o4.z = f2bf(fmaxf(acc2, 0.f)); o4.w = f2bf(fmaxf(acc3, 0.f));
                *reinterpret_cast<ushort4*>(orow + col) = o4;
            }
        }
    } else {
        // ---- fallback 3-pass (deg > 64; correctness-only) ----
        float ern[3] = {erv.x, erv.y, erv.z};
        float m[3] = {-3.402823466e38f, -3.402823466e38f, -3.402823466e38f};
        for (int i = lane; i < deg; i += 64) {
            int sv = ssrc[s0 + i];
            float4 elv = el[sv];
            float vv[3] = {elv.x, elv.y, elv.z};
#pragma unroll
            for (int h = 0; h < 3; h++) {
                float v = vv[h] + ern[h];
                v = v > 0.f ? v : NEG_SLOPE * v;
                m[h] = fmaxf(m[h], v);
            }
        }
#pragma unroll
        for (int h = 0; h < 3; h++) m[h] = wave_max64(m[h]);
        float s[3] = {0.f, 0.f, 0.f};
        for (int i = lane; i < deg; i += 64) {
            int sv = ssrc[s0 + i];
            float4 elv = el[sv];
            float vv[3] = {elv.x, elv.y, elv.z};
#pragma unroll
            for (int h = 0; h < 3; h++) {
                float v = vv[h] + ern[h];
                v = v > 0.f ? v : NEG_SLOPE * v;
                s[h] += __expf(v - m[h]);
            }
        }
#pragma unroll
        for (int h = 0; h < 3; h++) s[h] = 1.f / (wave_sum64(s[h]) + 1e-16f);
        constexpr int NC = (HD + 63) / 64;
        float acc[NC];
#pragma unroll
        for (int j = 0; j < NC; j++) acc[j] = 0.f;
        for (int i = 0; i < deg; i++) {
            int sv = ssrc[s0 + i];
            float4 elv = el[sv];
            float vv[3] = {elv.x, elv.y, elv.z};
            float a[3];
#pragma unroll
            for (int h = 0; h < 3; h++) {
                float v = vv[h] + ern[h];
                v = v > 0.f ? v : NEG_SLOPE * v;
                a[h] = __expf(v - m[h]) * s[h];
            }
            const unsigned short* zr = z + (size_t)sv * HD;
#pragma unroll
            for (int j = 0; j < NC; j++) {
                int c = lane + 64 * j;
                if (c < HD) acc[j] += a[c / D] * bf2f(zr[c]);
            }
        }
#pragma unroll
        for (int j = 0; j < NC; j++) {
            int c = lane + 64 * j;
            if (c < HD) {
                float o = fmaxf(acc[j], 0.f);
                if constexpr (VW == 2)
                    ((float*)xout_v)[(size_t)wid * HD + c] = o;
                else
                    ((unsigned short*)xout_v)[(size_t)wid * HD + c] = f2bf(o);
            }
        }
    }
}

// ---------------- Layer 2 GEMM: z2(bf16) = x1 @ W2 (50000x96 @ 96x192), fused el2/er2 ----------------

__global__ __launch_bounds__(256) void k_gemm2(const float* __restrict__ A,
                                               const float* __restrict__ B,
                                               const float* __restrict__ al,
                                               const float* __restrict__ ar,
                                               unsigned short* __restrict__ C,
                                               float* __restrict__ el2,
                                               float* __restrict__ er2, int M) {
    __shared__ float sAT[16][68];
    __shared__ float sB[16][64];
    int t = threadIdx.x;
    int n0 = blockIdx.x * 64;
    int h = blockIdx.y;
    int c0 = h * 64;
    int ty = t >> 4, tx = t & 15;
    float acc[4][4] = {};
    for (int k0 = 0; k0 < 96; k0 += 16) {
        int arow = t >> 2, aq = (t & 3) * 4;
        float4 av = make_float4(0.f, 0.f, 0.f, 0.f);
        if (n0 + arow < M)
            av = *reinterpret_cast<const float4*>(&A[(size_t)(n0 + arow) * 96 + k0 + aq]);
        sAT[aq + 0][arow] = av.x; sAT[aq + 1][arow] = av.y;
        sAT[aq + 2][arow] = av.z; sAT[aq + 3][arow] = av.w;
        int brow = t >> 4, bq = (t & 15) * 4;
        float4 bv = *reinterpret_cast<const float4*>(&B[(size_t)(k0 + brow) * 192 + c0 + bq]);
        *reinterpret_cast<float4*>(&sB[brow][bq]) = bv;
        __syncthreads();
#pragma unroll
        for (int kk = 0; kk < 16; kk++) {
            float4 a4 = *reinterpret_cast<const float4*>(&sAT[kk][ty * 4]);
            float4 b4 = *reinterpret_cast<const float4*>(&sB[kk][tx * 4]);
            float a[4] = {a4.x, a4.y, a4.z, a4.w};
            float b[4] = {b4.x, b4.y, b4.z, b4.w};
#pragma unroll
            for (int i = 0; i < 4; i++)
#pragma unroll
                for (int j = 0; j < 4; j++) acc[i][j] += a[i] * b[j];
        }
        __syncthreads();
    }
    float alv[4], arv[4];
#pragma unroll
    for (int j = 0; j < 4; j++) {
        alv[j] = al[c0 + tx * 4 + j];
        arv[j] = ar[c0 + tx * 4 + j];
    }
#pragma unroll
    for (int i = 0; i < 4; i++) {
        int r = n0 + ty * 4 + i;
        float pls = 0.f, prs = 0.f;
#pragma unroll
        for (int j = 0; j < 4; j++) { pls += acc[i][j] * alv[j]; prs += acc[i][j] * arv[j]; }
#pragma unroll
        for (int o = 1; o < 16; o <<= 1) { pls += __shfl_xor(pls, o); prs += __shfl_xor(prs, o); }
        if (r < M) {
            ushort4 o4;
            o4.x = f2bf(acc[i][0]); o4.y = f2bf(acc[i][1]);
            o4.z = f2bf(acc[i][2]); o4.w = f2bf(acc[i][3]);
            *reinterpret_cast<ushort4*>(&C[(size_t)r * 192 + c0 + tx * 4]) = o4;
            if (tx == 0) { el2[r * 4 + h] = pls; er2[r * 4 + h] = prs; }
        }
    }
}

// ---------------- graph mean-pool (graph_ids sorted); x2 is bf16 ----------------

__global__ __launch_bounds__(192) void k_pool(const unsigned short* __restrict__ x2,
                                              const int* __restrict__ gid,
                                              float* __restrict__ gsum, int n) {
    int base = blockIdx.x * 128;
    if (base >= n) return;
    int end = base + 128; if (end > n) end = n;
    int c = threadIdx.x;
    float acc = 0.f;
    int gprev = gid[base];
    for (int i = base; i < end; i++) {
        int g = gid[i];
        if (g != gprev) {
            atomicAdd(&gsum[gprev * 192 + c], acc);
            acc = 0.f;
            gprev = g;
        }
        acc += bf2f(x2[(size_t)i * 192 + c]);
    }
    atomicAdd(&gsum[gprev * 192 + c], acc);
}

// ---------------- MLP head: one wave per graph ----------------

__global__ __launch_bounds__(64) void k_head(const float* __restrict__ gsum,
                                             const int* __restrict__ gcnt,
                                             const float* __restrict__ d1w,
                                             const float* __restrict__ d1b,
                                             const float* __restrict__ d2w,
                                             const float* __restrict__ d2b,
                                             float* __restrict__ out, int G) {
    int g = blockIdx.x, j = threadIdx.x;
    float inv = 1.f / fmaxf((float)gcnt[g], 1.f);
    float h = d1b[j];
    for (int k = 0; k < 192; k++) h += (gsum[g * 192 + k] * inv) * d1w[(size_t)k * 64 + j];
    h = fmaxf(h, 0.f);
    float v = h * d2w[j];
    for (int off = 32; off; off >>= 1) v += __shfl_xor(v, off);
    if (j == 0) out[g] = v + d2b[0];
}

// ---------------- launch ----------------

extern "C" void kernel_launch(void* const* d_in, const int* in_sizes, int n_in,
                              void* d_out, int out_size, void* d_ws, size_t ws_size,
                              hipStream_t stream) {
    const float* feat = (const float*)d_in[0];
    const int* src = (const int*)d_in[1];
    const int* dst = (const int*)d_in[2];
    const int* gid = (const int*)d_in[3];
    const float* W1 = (const float*)d_in[4];
    const float* al1 = (const float*)d_in[5];
    const float* ar1 = (const float*)d_in[6];
    const float* W2 = (const float*)d_in[7];
    const float* al2 = (const float*)d_in[8];
    const float* ar2 = (const float*)d_in[9];
    const float* d1w = (const float*)d_in[10];
    const float* d1b = (const float*)d_in[11];
    const float* d2w = (const float*)d_in[12];
    const float* d2b = (const float*)d_in[13];
    float* out = (float*)d_out;
    const int N = in_sizes[0] / 10;   // 50000
    const int E = in_sizes[1];        // 800000
    const int G = out_size;           // 128

    char* p = (char*)d_ws;
    auto take = [&](size_t bytes) -> char* {
        char* r = p;
        p += (bytes + 255) & ~(size_t)255;
        return r;
    };
    unsigned short* z1 = (unsigned short*)take((size_t)N * 96 * 2);  // 9.6MB
    float* x1 = (float*)take((size_t)N * 96 * 4);                    // 19.2MB (contiguous after z1)
    // x2 (bf16, N*192*2 = 19.2MB) aliases [z1 .. z1+19.2MB): z1 and the
    // start of x1, both dead by the time agg2 writes it.
    unsigned short* x2 = z1;
    unsigned short* z2 = (unsigned short*)take((size_t)N * 192 * 2);
    float4* el1 = (float4*)take((size_t)N * 16);
    float4* er1 = (float4*)take((size_t)N * 16);
    float* el2 = (float*)take((size_t)N * 16);
    float* er2 = (float*)take((size_t)N * 16);
    int* degcur = (int*)take((size_t)2 * N * 4);
    int* deg = degcur;
    int* cursor = degcur + N;
    int* row_start = (int*)take((size_t)(N + 1) * 4);
    int* ssrc = (int*)take((size_t)E * 4);
    float* gsum = (float*)take((size_t)G * 192 * 4 + (size_t)G * 4);
    int* gcnt = (int*)(gsum + (size_t)G * 192);

    hipMemsetAsync(degcur, 0, (size_t)2 * N * 4, stream);
    hipMemsetAsync(gsum, 0, (size_t)G * 192 * 4 + (size_t)G * 4, stream);

    // CSR build (bucket src ids by dst)
    k_hist<<<(E + 255) / 256, 256, 0, stream>>>(dst, deg, E);
    k_scan<<<1, 1024, 0, stream>>>(deg, row_start, N);
    k_scatter<<<(E + 255) / 256, 256, 0, stream>>>(dst, src, row_start, cursor, ssrc, E);

    // Layer 1
    k_gemm1<<<(N + 255) / 256, 256, 0, stream>>>(feat, W1, al1, ar1, gid, z1, el1, er1, gcnt, N);
    k_agg<32, 2><<<((size_t)N * 64 + 255) / 256, 256, 0, stream>>>(
        z1, el1, er1, row_start, ssrc, (void*)x1, N);
    // Layer 2 (el2/er2 fused into GEMM epilogue)
    k_gemm2<<<dim3((N + 63) / 64, 3), 256, 0, stream>>>(x1, W2, al2, ar2, z2, el2, er2, N);
    k_agg<64, 4><<<((size_t)N * 64 + 255) / 256, 256, 0, stream>>>(
        z2, (const float4*)el2, (const float4*)er2, row_start, ssrc, (void*)x2, N);
    // Pool + head
    k_pool<<<(N + 127) / 128, 192, 0, stream>>>(x2, gid, gsum, N);
    k_head<<<G, 64, 0, stream>>>(gsum, gcnt, d1w, d1b, d2w, d2b, out, G);
}

// Round 6
// 460.764 us; speedup vs baseline: 1.6253x; 1.2488x over previous
//
#include <hip/hip_runtime.h>
#include <hip/hip_bf16.h>

#define NEG_SLOPE 0.2f

__device__ __forceinline__ float wave_max64(float v) {
    for (int o = 32; o; o >>= 1) v = fmaxf(v, __shfl_xor(v, o));
    return v;
}
__device__ __forceinline__ float wave_sum64(float v) {
    for (int o = 32; o; o >>= 1) v += __shfl_xor(v, o);
    return v;
}
__device__ __forceinline__ unsigned short f2bf(float f) {
    unsigned int u = __float_as_uint(f);
    unsigned int r = (u + 0x7fffu + ((u >> 16) & 1u)) >> 16;
    return (unsigned short)r;
}
__device__ __forceinline__ float bf2f(unsigned short u) {
    return __uint_as_float(((unsigned int)u) << 16);
}

// ---------------- CSR build ----------------

__global__ void k_hist(const int* __restrict__ dst, int* __restrict__ deg, int E) {
    int e = blockIdx.x * blockDim.x + threadIdx.x;
    if (e < E) atomicAdd(&deg[dst[e]], 1);
}

__global__ __launch_bounds__(1024) void k_scan(const int* __restrict__ deg,
                                               int* __restrict__ row_start, int n) {
    __shared__ int sdata[1024];
    int tid = threadIdx.x;
    const int per = 52;
    int begin = tid * per;
    int end = begin + per; if (end > n) end = n;
    int sum = 0;
    int i = begin;
    for (; i + 3 < end; i += 4) {
        int4 v = *reinterpret_cast<const int4*>(deg + i);
        sum += v.x + v.y + v.z + v.w;
    }
    for (; i < end; i++) sum += deg[i];
    sdata[tid] = sum;
    __syncthreads();
    for (int off = 1; off < 1024; off <<= 1) {
        int t = (tid >= off) ? sdata[tid - off] : 0;
        __syncthreads();
        sdata[tid] += t;
        __syncthreads();
    }
    int run = sdata[tid] - sum;
    for (int j = begin; j < end; j++) { row_start[j] = run; run += deg[j]; }
    if (tid == 1023) row_start[n] = sdata[1023];
}

__global__ void k_scatter(const int* __restrict__ dst, const int* __restrict__ src,
                          const int* __restrict__ row_start, int* __restrict__ cursor,
                          int* __restrict__ ssrc, int E) {
    int e = blockIdx.x * blockDim.x + threadIdx.x;
    if (e < E) {
        int d = dst[e];
        int pos = row_start[d] + atomicAdd(&cursor[d], 1);
        ssrc[pos] = src[e];
    }
}

// ---------------- per-graph node counts via binary search (graph_ids sorted) ----------------

__global__ __launch_bounds__(128) void k_bounds(const int* __restrict__ gid,
                                                int* __restrict__ gcnt, int n, int G) {
    int g = threadIdx.x;  // one thread per graph
    if (g >= G) return;
    int lo0 = 0, hi0 = n;
    while (lo0 < hi0) { int mid = (lo0 + hi0) >> 1; if (gid[mid] < g) lo0 = mid + 1; else hi0 = mid; }
    int lo1 = lo0, hi1 = n;
    while (lo1 < hi1) { int mid = (lo1 + hi1) >> 1; if (gid[mid] < g + 1) lo1 = mid + 1; else hi1 = mid; }
    gcnt[g] = lo1 - lo0;
}

// ---------------- Layer 1 GEMM: z1(bf16) = feat @ W1, fused el1/er1 ----------------

__global__ __launch_bounds__(256) void k_gemm1(const float* __restrict__ feat,
                                               const float* __restrict__ W1,
                                               const float* __restrict__ al,
                                               const float* __restrict__ ar,
                                               unsigned short* __restrict__ z1,
                                               float4* __restrict__ el1,
                                               float4* __restrict__ er1, int n) {
    __shared__ float sW[960], sal[96], sar[96];
    for (int i = threadIdx.x; i < 960; i += 256) sW[i] = W1[i];
    for (int i = threadIdx.x; i < 96; i += 256) { sal[i] = al[i]; sar[i] = ar[i]; }
    __syncthreads();
    int nd = blockIdx.x * 256 + threadIdx.x;
    if (nd >= n) return;
    float x[10];
#pragma unroll
    for (int k = 0; k < 10; k++) x[k] = feat[(size_t)nd * 10 + k];
    float el[3] = {0.f, 0.f, 0.f}, er[3] = {0.f, 0.f, 0.f};
#pragma unroll
    for (int h = 0; h < 3; h++) {
#pragma unroll
        for (int d0 = 0; d0 < 32; d0 += 4) {
            ushort4 o;
            unsigned short* op = &o.x;
#pragma unroll
            for (int q = 0; q < 4; q++) {
                int c = h * 32 + d0 + q;
                float acc = 0.f;
#pragma unroll
                for (int k = 0; k < 10; k++) acc += x[k] * sW[k * 96 + c];
                op[q] = f2bf(acc);
                el[h] += acc * sal[c];
                er[h] += acc * sar[c];
            }
            *reinterpret_cast<ushort4*>(&z1[(size_t)nd * 96 + h * 32 + d0]) = o;
        }
    }
    el1[nd] = make_float4(el[0], el[1], el[2], 0.f);
    er1[nd] = make_float4(er[0], er[1], er[2], 0.f);
}

// ---------------- GAT aggregation: wave per dst node ----------------
// z is bf16. VW = bf16 columns per lane (2 for HD=96 -> fp32 out; 4 for HD=192 -> bf16 out).

template <int D, int VW>
__global__ __launch_bounds__(256) void k_agg(const unsigned short* __restrict__ z,
                                             const float4* __restrict__ el,
                                             const float4* __restrict__ er,
                                             const int* __restrict__ row_start,
                                             const int* __restrict__ ssrc,
                                             void* __restrict__ xout_v, int n) {
    constexpr int H = 3;
    constexpr int HD = H * D;
    constexpr int NL = HD / VW;  // 48
    __shared__ float pl[4][3 * 68];
    int wid = (blockIdx.x * blockDim.x + threadIdx.x) >> 6;
    int lane = threadIdx.x & 63;
    int w = threadIdx.x >> 6;
    if (wid >= n) return;
    int s0 = row_start[wid];
    int deg = row_start[wid + 1] - s0;
    if (deg <= 0) {
        if (lane < NL) {
            if constexpr (VW == 2) {
                float* orow = (float*)xout_v + (size_t)wid * HD;
                *reinterpret_cast<float2*>(orow + VW * lane) = make_float2(0.f, 0.f);
            } else {
                unsigned short* orow = (unsigned short*)xout_v + (size_t)wid * HD;
                *reinterpret_cast<ushort4*>(orow + VW * lane) = make_ushort4(0, 0, 0, 0);
            }
        }
        return;
    }
    float4 erv = er[wid];
    int hh = (VW * lane) / D;
    if (hh >= H) hh = H - 1;

    if (deg <= 64) {
        bool act = lane < deg;
        int sv = act ? ssrc[s0 + lane] : 0;
        float4 elv = el[sv];
        float v0 = elv.x + erv.x; v0 = v0 > 0.f ? v0 : NEG_SLOPE * v0;
        float v1 = elv.y + erv.y; v1 = v1 > 0.f ? v1 : NEG_SLOPE * v1;
        float v2 = elv.z + erv.z; v2 = v2 > 0.f ? v2 : NEG_SLOPE * v2;
        if (!act) { v0 = -3.402823466e38f; v1 = v0; v2 = v0; }
        float m0 = wave_max64(v0), m1 = wave_max64(v1), m2 = wave_max64(v2);
        float p0 = act ? __expf(v0 - m0) : 0.f;
        float p1 = act ? __expf(v1 - m1) : 0.f;
        float p2 = act ? __expf(v2 - m2) : 0.f;
        float i0 = 1.f / (wave_sum64(p0) + 1e-16f);
        float i1 = 1.f / (wave_sum64(p1) + 1e-16f);
        float i2 = 1.f / (wave_sum64(p2) + 1e-16f);
        pl[w][0 * 68 + lane] = p0 * i0;
        pl[w][1 * 68 + lane] = p1 * i1;
        pl[w][2 * 68 + lane] = p2 * i2;
        int zofs = sv * HD;
        const float* pt = &pl[w][hh * 68];

        int col = VW * (lane < NL ? lane : NL - 1);
        float acc0 = 0.f, acc1 = 0.f, acc2 = 0.f, acc3 = 0.f;
#pragma unroll 4
        for (int i = 0; i < deg; i++) {
            int zo = __shfl(zofs, i);
            float a = pt[i];
            const unsigned short* zp = z + zo + col;
            if constexpr (VW == 2) {
                ushort2 zv = *reinterpret_cast<const ushort2*>(zp);
                acc0 += a * bf2f(zv.x); acc1 += a * bf2f(zv.y);
            } else {
                ushort4 zv = *reinterpret_cast<const ushort4*>(zp);
                acc0 += a * bf2f(zv.x); acc1 += a * bf2f(zv.y);
                acc2 += a * bf2f(zv.z); acc3 += a * bf2f(zv.w);
            }
        }
        if (lane < NL) {
            if constexpr (VW == 2) {
                float* orow = (float*)xout_v + (size_t)wid * HD;
                *reinterpret_cast<float2*>(orow + col) =
                    make_float2(fmaxf(acc0, 0.f), fmaxf(acc1, 0.f));
            } else {
                unsigned short* orow = (unsigned short*)xout_v + (size_t)wid * HD;
                ushort4 o4;
                o4.x = f2bf(fmaxf(acc0, 0.f)); o4.y = f2bf(fmaxf(acc1, 0.f));
                o4.z = f2bf(fmaxf(acc2, 0.f)); o4.w = f2bf(fmaxf(acc3, 0.f));
                *reinterpret_cast<ushort4*>(orow + col) = o4;
            }
        }
    } else {
        // ---- fallback 3-pass (deg > 64; correctness-only) ----
        float ern[3] = {erv.x, erv.y, erv.z};
        float m[3] = {-3.402823466e38f, -3.402823466e38f, -3.402823466e38f};
        for (int i = lane; i < deg; i += 64) {
            int sv = ssrc[s0 + i];
            float4 elv = el[sv];
            float vv[3] = {elv.x, elv.y, elv.z};
#pragma unroll
            for (int h = 0; h < 3; h++) {
                float v = vv[h] + ern[h];
                v = v > 0.f ? v : NEG_SLOPE * v;
                m[h] = fmaxf(m[h], v);
            }
        }
#pragma unroll
        for (int h = 0; h < 3; h++) m[h] = wave_max64(m[h]);
        float s[3] = {0.f, 0.f, 0.f};
        for (int i = lane; i < deg; i += 64) {
            int sv = ssrc[s0 + i];
            float4 elv = el[sv];
            float vv[3] = {elv.x, elv.y, elv.z};
#pragma unroll
            for (int h = 0; h < 3; h++) {
                float v = vv[h] + ern[h];
                v = v > 0.f ? v : NEG_SLOPE * v;
                s[h] += __expf(v - m[h]);
            }
        }
#pragma unroll
        for (int h = 0; h < 3; h++) s[h] = 1.f / (wave_sum64(s[h]) + 1e-16f);
        constexpr int NC = (HD + 63) / 64;
        float acc[NC];
#pragma unroll
        for (int j = 0; j < NC; j++) acc[j] = 0.f;
        for (int i = 0; i < deg; i++) {
            int sv = ssrc[s0 + i];
            float4 elv = el[sv];
            float vv[3] = {elv.x, elv.y, elv.z};
            float a[3];
#pragma unroll
            for (int h = 0; h < 3; h++) {
                float v = vv[h] + ern[h];
                v = v > 0.f ? v : NEG_SLOPE * v;
                a[h] = __expf(v - m[h]) * s[h];
            }
            const unsigned short* zr = z + (size_t)sv * HD;
#pragma unroll
            for (int j = 0; j < NC; j++) {
                int c = lane + 64 * j;
                if (c < HD) acc[j] += a[c / D] * bf2f(zr[c]);
            }
        }
#pragma unroll
        for (int j = 0; j < NC; j++) {
            int c = lane + 64 * j;
            if (c < HD) {
                float o = fmaxf(acc[j], 0.f);
                if constexpr (VW == 2)
                    ((float*)xout_v)[(size_t)wid * HD + c] = o;
                else
                    ((unsigned short*)xout_v)[(size_t)wid * HD + c] = f2bf(o);
            }
        }
    }
}

// ---------------- Layer 2 GEMM: z2(bf16) = x1 @ W2 (50000x96 @ 96x192), fused el2/er2 ----------------

__global__ __launch_bounds__(256) void k_gemm2(const float* __restrict__ A,
                                               const float* __restrict__ B,
                                               const float* __restrict__ al,
                                               const float* __restrict__ ar,
                                               unsigned short* __restrict__ C,
                                               float* __restrict__ el2,
                                               float* __restrict__ er2, int M) {
    __shared__ float sAT[16][68];
    __shared__ float sB[16][64];
    int t = threadIdx.x;
    int n0 = blockIdx.x * 64;
    int h = blockIdx.y;
    int c0 = h * 64;
    int ty = t >> 4, tx = t & 15;
    float acc[4][4] = {};
    for (int k0 = 0; k0 < 96; k0 += 16) {
        int arow = t >> 2, aq = (t & 3) * 4;
        float4 av = make_float4(0.f, 0.f, 0.f, 0.f);
        if (n0 + arow < M)
            av = *reinterpret_cast<const float4*>(&A[(size_t)(n0 + arow) * 96 + k0 + aq]);
        sAT[aq + 0][arow] = av.x; sAT[aq + 1][arow] = av.y;
        sAT[aq + 2][arow] = av.z; sAT[aq + 3][arow] = av.w;
        int brow = t >> 4, bq = (t & 15) * 4;
        float4 bv = *reinterpret_cast<const float4*>(&B[(size_t)(k0 + brow) * 192 + c0 + bq]);
        *reinterpret_cast<float4*>(&sB[brow][bq]) = bv;
        __syncthreads();
#pragma unroll
        for (int kk = 0; kk < 16; kk++) {
            float4 a4 = *reinterpret_cast<const float4*>(&sAT[kk][ty * 4]);
            float4 b4 = *reinterpret_cast<const float4*>(&sB[kk][tx * 4]);
            float a[4] = {a4.x, a4.y, a4.z, a4.w};
            float b[4] = {b4.x, b4.y, b4.z, b4.w};
#pragma unroll
            for (int i = 0; i < 4; i++)
#pragma unroll
                for (int j = 0; j < 4; j++) acc[i][j] += a[i] * b[j];
        }
        __syncthreads();
    }
    float alv[4], arv[4];
#pragma unroll
    for (int j = 0; j < 4; j++) {
        alv[j] = al[c0 + tx * 4 + j];
        arv[j] = ar[c0 + tx * 4 + j];
    }
#pragma unroll
    for (int i = 0; i < 4; i++) {
        int r = n0 + ty * 4 + i;
        float pls = 0.f, prs = 0.f;
#pragma unroll
        for (int j = 0; j < 4; j++) { pls += acc[i][j] * alv[j]; prs += acc[i][j] * arv[j]; }
#pragma unroll
        for (int o = 1; o < 16; o <<= 1) { pls += __shfl_xor(pls, o); prs += __shfl_xor(prs, o); }
        if (r < M) {
            ushort4 o4;
            o4.x = f2bf(acc[i][0]); o4.y = f2bf(acc[i][1]);
            o4.z = f2bf(acc[i][2]); o4.w = f2bf(acc[i][3]);
            *reinterpret_cast<ushort4*>(&C[(size_t)r * 192 + c0 + tx * 4]) = o4;
            if (tx == 0) { el2[r * 4 + h] = pls; er2[r * 4 + h] = prs; }
        }
    }
}

// ---------------- graph mean-pool (graph_ids sorted); x2 is bf16 ----------------

__global__ __launch_bounds__(192) void k_pool(const unsigned short* __restrict__ x2,
                                              const int* __restrict__ gid,
                                              float* __restrict__ gsum, int n) {
    int base = blockIdx.x * 128;
    if (base >= n) return;
    int end = base + 128; if (end > n) end = n;
    int c = threadIdx.x;
    float acc = 0.f;
    int gprev = gid[base];
    for (int i = base; i < end; i++) {
        int g = gid[i];
        if (g != gprev) {
            atomicAdd(&gsum[gprev * 192 + c], acc);
            acc = 0.f;
            gprev = g;
        }
        acc += bf2f(x2[(size_t)i * 192 + c]);
    }
    atomicAdd(&gsum[gprev * 192 + c], acc);
}

// ---------------- MLP head: one wave per graph ----------------

__global__ __launch_bounds__(64) void k_head(const float* __restrict__ gsum,
                                             const int* __restrict__ gcnt,
                                             const float* __restrict__ d1w,
                                             const float* __restrict__ d1b,
                                             const float* __restrict__ d2w,
                                             const float* __restrict__ d2b,
                                             float* __restrict__ out, int G) {
    int g = blockIdx.x, j = threadIdx.x;
    float inv = 1.f / fmaxf((float)gcnt[g], 1.f);
    float h = d1b[j];
    for (int k = 0; k < 192; k++) h += (gsum[g * 192 + k] * inv) * d1w[(size_t)k * 64 + j];
    h = fmaxf(h, 0.f);
    float v = h * d2w[j];
    for (int off = 32; off; off >>= 1) v += __shfl_xor(v, off);
    if (j == 0) out[g] = v + d2b[0];
}

// ---------------- launch ----------------

extern "C" void kernel_launch(void* const* d_in, const int* in_sizes, int n_in,
                              void* d_out, int out_size, void* d_ws, size_t ws_size,
                              hipStream_t stream) {
    const float* feat = (const float*)d_in[0];
    const int* src = (const int*)d_in[1];
    const int* dst = (const int*)d_in[2];
    const int* gid = (const int*)d_in[3];
    const float* W1 = (const float*)d_in[4];
    const float* al1 = (const float*)d_in[5];
    const float* ar1 = (const float*)d_in[6];
    const float* W2 = (const float*)d_in[7];
    const float* al2 = (const float*)d_in[8];
    const float* ar2 = (const float*)d_in[9];
    const float* d1w = (const float*)d_in[10];
    const float* d1b = (const float*)d_in[11];
    const float* d2w = (const float*)d_in[12];
    const float* d2b = (const float*)d_in[13];
    float* out = (float*)d_out;
    const int N = in_sizes[0] / 10;   // 50000
    const int E = in_sizes[1];        // 800000
    const int G = out_size;           // 128

    char* p = (char*)d_ws;
    auto take = [&](size_t bytes) -> char* {
        char* r = p;
        p += (bytes + 255) & ~(size_t)255;
        return r;
    };
    unsigned short* z1 = (unsigned short*)take((size_t)N * 96 * 2);  // 9.6MB
    float* x1 = (float*)take((size_t)N * 96 * 4);                    // 19.2MB (contiguous after z1)
    // x2 (bf16, N*192*2 = 19.2MB) aliases [z1 .. z1+19.2MB): z1 and the
    // start of x1, both dead by the time agg2 writes it.
    unsigned short* x2 = z1;
    unsigned short* z2 = (unsigned short*)take((size_t)N * 192 * 2);
    float4* el1 = (float4*)take((size_t)N * 16);
    float4* er1 = (float4*)take((size_t)N * 16);
    float* el2 = (float*)take((size_t)N * 16);
    float* er2 = (float*)take((size_t)N * 16);
    int* degcur = (int*)take((size_t)2 * N * 4);
    int* deg = degcur;
    int* cursor = degcur + N;
    int* row_start = (int*)take((size_t)(N + 1) * 4);
    int* ssrc = (int*)take((size_t)E * 4);
    float* gsum = (float*)take((size_t)G * 192 * 4 + (size_t)G * 4);
    int* gcnt = (int*)(gsum + (size_t)G * 192);

    hipMemsetAsync(degcur, 0, (size_t)2 * N * 4, stream);
    hipMemsetAsync(gsum, 0, (size_t)G * 192 * 4, stream);

    // CSR build (bucket src ids by dst)
    k_hist<<<(E + 255) / 256, 256, 0, stream>>>(dst, deg, E);
    k_scan<<<1, 1024, 0, stream>>>(deg, row_start, N);
    k_scatter<<<(E + 255) / 256, 256, 0, stream>>>(dst, src, row_start, cursor, ssrc, E);

    // Per-graph counts: binary search on sorted graph_ids (no atomics)
    k_bounds<<<1, 128, 0, stream>>>(gid, gcnt, N, G);

    // Layer 1
    k_gemm1<<<(N + 255) / 256, 256, 0, stream>>>(feat, W1, al1, ar1, z1, el1, er1, N);
    k_agg<32, 2><<<((size_t)N * 64 + 255) / 256, 256, 0, stream>>>(
        z1, el1, er1, row_start, ssrc, (void*)x1, N);
    // Layer 2 (el2/er2 fused into GEMM epilogue)
    k_gemm2<<<dim3((N + 63) / 64, 3), 256, 0, stream>>>(x1, W2, al2, ar2, z2, el2, er2, N);
    k_agg<64, 4><<<((size_t)N * 64 + 255) / 256, 256, 0, stream>>>(
        z2, (const float4*)el2, (const float4*)er2, row_start, ssrc, (void*)x2, N);
    // Pool + head
    k_pool<<<(N + 127) / 128, 192, 0, stream>>>(x2, gid, gsum, N);
    k_head<<<G, 64, 0, stream>>>(gsum, gcnt, d1w, d1b, d2w, d2b, out, G);
}